// Round 18
// baseline (75.066 us; speedup 1.0000x reference)
//
#include <hip/hip_runtime.h>
#include <hip/hip_fp16.h>

// src:  [1,2,160,192,224] f32, flow: [1,3,160,192,224] f32, out: [1,2,160,192,224] f32
constexpr int D = 160, H = 192, W = 224;
constexpr int HW = H * W;
constexpr int N = D * HW;

// R16 + circular-z double-tile: each block does TWO z-adjacent 8x8x32 sub-tiles.
// Staged window 16x16x40 half2 = 40 KB (4 blocks/CU). Sub-tile 1 re-stages only
// the 8 NEW z-slabs (slab = z & 15) -> z-halo HBM re-fetch eliminated.
constexpr int HA = 4;
constexpr int SZ = 16, SY = 16, SX = 40;   // staged extents (half2 units in x)
constexpr int SXP = 20;                     // staged x-pairs per row
constexpr int NTHR = 512;
constexpr int TPB = SZ * SY * SX;           // 10240 half2 = 40 KB

typedef float f4 __attribute__((ext_vector_type(4)));

struct h2p { __half2 a, b; };               // (ch0,ch1)@x , (ch0,ch1)@x+1
__device__ __forceinline__ h2p    ld_pair(const __half2* p){ h2p v; __builtin_memcpy(&v,p,8); return v; }
__device__ __forceinline__ void   st_pair(__half2* p, h2p v){ __builtin_memcpy(p,&v,8); }
__device__ __forceinline__ float2 ld2f(const float* p){ float2 v; __builtin_memcpy(&v,p,8); return v; }
__device__ __forceinline__ f4     ld4f(const float* p){ f4 v; __builtin_memcpy(&v,p,16); return v; }
__device__ __forceinline__ void   st4f(float* p, f4 v){ __builtin_memcpy(p,&v,16); }

__global__ __launch_bounds__(NTHR, 8) void warp3d_r17_kernel(
    const float* __restrict__ src,
    const float* __restrict__ flow,
    float* __restrict__ out)
{
    __shared__ __half2 tile[TPB];           // 40 KB

    const float* src0 = src;
    const float* src1 = src + N;
    const float* f0 = flow, * f1 = flow + N, * f2 = flow + 2 * N;
    float* out0 = out, * out1 = out + N;

    const int tid = threadIdx.x;
    const int bx = blockIdx.x, by = blockIdx.y, bzz = blockIdx.z;  // bzz in [0,10)
    const int zb0 = bzz << 4;               // output z base of sub-tile 0 (16 z per block)
    const int tz0 = zb0 - HA;               // staged z origin (slab 0)
    const int ty0 = by * 8 - HA;
    const int tx0 = bx * 32 - HA;

    // ---- flow quads for BOTH sub-tiles (loaded early; latency hides under stage0) ----
    const int qm = tid & 7, qd = tid >> 3;  // qd in [0,64)
    const int lx = qm << 2, ly = qd & 7, lz = qd >> 3;
    const int vi0 = ((zb0 + lz) * H + by * 8 + ly) * W + bx * 32 + lx;
    const int vi1 = vi0 + 8 * HW;
    const f4 fzA = ld4f(f0 + vi0), fyA = ld4f(f1 + vi0), fxA = ld4f(f2 + vi0);
    const f4 fzB = ld4f(f0 + vi1), fyB = ld4f(f1 + vi1), fxB = ld4f(f2 + vi1);

    // ---- staging helper: one x-pair row element (R12-verbatim math) ----
    auto stage_pair = [&](int row, int col, int gz) {
        const int gy = min(max(ty0 + (row & 15), 0), H - 1);
        const int b  = tx0 + (col << 1);
        const int bc = min(max(b, 0), W - 2);
        const bool s0 = (min(max(b,     0), W - 1) > bc);
        const bool s1 = (min(max(b + 1, 0), W - 1) > bc);
        const int ga = (gz * H + gy) * W + bc;
        const float2 a = ld2f(src0 + ga);
        const float2 c = ld2f(src1 + ga);
        h2p v;
        v.a = __floats2half2_rn(s0 ? a.y : a.x, s0 ? c.y : c.x);
        v.b = __floats2half2_rn(s1 ? a.y : a.x, s1 ? c.y : c.x);
        st_pair(&tile[row * SX + (col << 1)], v);
    };

    // ---- gather one sub-tile (k = 0 or 1); slab = (a0 + 8k) & 15 circular ----
    auto gather = [&](int k, const f4& fz4, const f4& fy4, const f4& fx4, int vi, int zb) {
        const int tzk = zb - HA;
        const float pz_b = (float)(zb + lz);
        const float py_b = (float)(by * 8 + ly);
        const float px_b = (float)(bx * 32 + lx);

        float a0s[4], a1s[4];

        #pragma unroll
        for (int i = 0; i < 4; ++i) {
            const float pz = fz4[i] + pz_b;
            const float py = fy4[i] + py_b;
            const float px = fx4[i] + (px_b + (float)i);

            const float z0f = floorf(pz), y0f = floorf(py), x0f = floorf(px);
            const float fz = pz - z0f, fy = py - y0f, fx = px - x0f;
            const int z0 = (int)z0f, y0 = (int)y0f, x0 = (int)x0f;

            // zeros padding folded into per-axis weights (validity on GLOBAL coords)
            const float wz0 = ((unsigned)z0       < (unsigned)D) ? (1.0f - fz) : 0.0f;
            const float wz1 = ((unsigned)(z0 + 1) < (unsigned)D) ? fz          : 0.0f;
            const float wy0 = ((unsigned)y0       < (unsigned)H) ? (1.0f - fy) : 0.0f;
            const float wy1 = ((unsigned)(y0 + 1) < (unsigned)H) ? fy          : 0.0f;
            const float wx0 = ((unsigned)x0       < (unsigned)W) ? (1.0f - fx) : 0.0f;
            const float wx1 = ((unsigned)(x0 + 1) < (unsigned)W) ? fx          : 0.0f;

            const int a0 = z0 - tzk;
            const int b0 = y0 - ty0;
            const int u0 = x0 - tx0;
            const bool intile = ((unsigned)a0 < (unsigned)(SZ - 1)) &&
                                ((unsigned)b0 < (unsigned)(SY - 1)) &&
                                ((unsigned)u0 < (unsigned)(SX - 1));

            if (intile) {
                const __half2 wxh0 = __float2half2_rn(wx0);
                const __half2 wxh1 = __float2half2_rn(wx1);
                const __half2 w00h = __float2half2_rn(wz0 * wy0);
                const __half2 w01h = __float2half2_rn(wz0 * wy1);
                const __half2 w10h = __float2half2_rn(wz1 * wy0);
                const __half2 w11h = __float2half2_rn(wz1 * wy1);

                const int slab0 = (a0 + 8 * k) & 15;
                const int slab1 = (a0 + 8 * k + 1) & 15;
                const int r00 = (slab0 * SY + b0) * SX + u0;
                const int r10 = (slab1 * SY + b0) * SX + u0;
                const h2p q00 = ld_pair(&tile[r00]);
                const h2p q01 = ld_pair(&tile[r00 + SX]);
                const h2p q10 = ld_pair(&tile[r10]);
                const h2p q11 = ld_pair(&tile[r10 + SX]);

                const __half2 xl00 = __hfma2(q00.b, wxh1, __hmul2(q00.a, wxh0));
                const __half2 xl01 = __hfma2(q01.b, wxh1, __hmul2(q01.a, wxh0));
                const __half2 xl10 = __hfma2(q10.b, wxh1, __hmul2(q10.a, wxh0));
                const __half2 xl11 = __hfma2(q11.b, wxh1, __hmul2(q11.a, wxh0));

                const __half2 acc = __hfma2(xl11, __float2half2_rn(wz1 * wy1),
                                    __hfma2(xl10, w10h,
                                    __hfma2(xl01, w01h,
                                    __hmul2(xl00, w00h))));
                const float2 g = __half22float2(acc);
                a0s[i] = g.x;
                a1s[i] = g.y;
            } else {
                // |flow| >= 4 near a tile face (P ~ 1e-5): exact fp32 global fallback
                const float w00 = wz0 * wy0, w01 = wz0 * wy1;
                const float w10 = wz1 * wy0, w11 = wz1 * wy1;
                const int zc0 = min(max(z0, 0), D - 1), zc1 = min(max(z0 + 1, 0), D - 1);
                const int yc0 = min(max(y0, 0), H - 1), yc1 = min(max(y0 + 1, 0), H - 1);
                const int xc0 = min(max(x0, 0), W - 1), xc1 = min(max(x0 + 1, 0), W - 1);
                const int g00 = (zc0 * H + yc0) * W, g01 = (zc0 * H + yc1) * W;
                const int g10 = (zc1 * H + yc0) * W, g11 = (zc1 * H + yc1) * W;
                a0s[i] = w00 * (wx0 * src0[g00 + xc0] + wx1 * src0[g00 + xc1])
                       + w01 * (wx0 * src0[g01 + xc0] + wx1 * src0[g01 + xc1])
                       + w10 * (wx0 * src0[g10 + xc0] + wx1 * src0[g10 + xc1])
                       + w11 * (wx0 * src0[g11 + xc0] + wx1 * src0[g11 + xc1]);
                a1s[i] = w00 * (wx0 * src1[g00 + xc0] + wx1 * src1[g00 + xc1])
                       + w01 * (wx0 * src1[g01 + xc0] + wx1 * src1[g01 + xc1])
                       + w10 * (wx0 * src1[g10 + xc0] + wx1 * src1[g10 + xc1])
                       + w11 * (wx0 * src1[g11 + xc0] + wx1 * src1[g11 + xc1]);
            }
        }

        f4 o0 = { a0s[0], a0s[1], a0s[2], a0s[3] };
        f4 o1 = { a1s[0], a1s[1], a1s[2], a1s[3] };
        st4f(out0 + vi, o0);
        st4f(out1 + vi, o1);
    };

    // ---- stage0: slabs 0..15 (5120 pairs, 10/thread, R12-verbatim flat index) ----
    #pragma unroll 2
    for (int k = 0; k < 10; ++k) {
        const int pi  = tid + k * NTHR;
        const int row = pi / SXP;
        const int col = pi - row * SXP;
        const int gz  = min(max(tz0 + (row >> 4), 0), D - 1);
        stage_pair(row, col, gz);
    }
    __syncthreads();

    gather(0, fzA, fyA, fxA, vi0, zb0);
    __syncthreads();                         // all reads of slabs 0..7 done

    // ---- stage1: new slabs z = tz0+16 .. tz0+23 -> LDS slabs 0..7 (5/thread) ----
    #pragma unroll
    for (int k = 0; k < 5; ++k) {
        const int pi  = tid + k * NTHR;
        const int row = pi / SXP;            // [0,128): slab (row>>4) in [0,8)
        const int col = pi - row * SXP;
        const int gz  = min(max(tz0 + 16 + (row >> 4), 0), D - 1);
        stage_pair(row, col, gz);
    }
    __syncthreads();

    gather(1, fzB, fyB, fxB, vi1, zb0 + 8);
}

extern "C" void kernel_launch(void* const* d_in, const int* in_sizes, int n_in,
                              void* d_out, int out_size, void* d_ws, size_t ws_size,
                              hipStream_t stream) {
    const float* src  = (const float*)d_in[0];
    const float* flow = (const float*)d_in[1];
    float* out = (float*)d_out;

    dim3 grid(W / 32, H / 8, D / 16);        // 7 x 24 x 10 = 1680 blocks, 2 z-tiles each
    warp3d_r17_kernel<<<grid, NTHR, 0, stream>>>(src, flow, out);
}

// Round 19
// 57.395 us; speedup vs baseline: 1.3079x; 1.3079x over previous
//
#include <hip/hip_runtime.h>
#include <hip/hip_fp16.h>

// src:  [1,2,160,192,224] f32, flow: [1,3,160,192,224] f32, out: [1,2,160,192,224] f32
constexpr int D = 160, H = 192, W = 224;
constexpr int HW = H * W;
constexpr int N = D * HW;

// R16 (best: 60.0 us) + ONE graft: staging split into load-all (20 loads in
// flight, ONE vmcnt wait) then commit (cvt+ds_write). Was unroll-2 = 5 waits.
// Tile 8x8x32 outputs, halo 4 -> staged 16x16x40 half2 = 40 KB -> 4 blocks/CU.
constexpr int BZ = 8, BY = 8, BX = 32;
constexpr int HA = 4;
constexpr int SZ = 16, SY = 16, SX = 40;   // staged extents (half2 elements in x)
constexpr int SXP = 20;                     // staged x-pairs per row
constexpr int NTHR = 512;
constexpr int NPP = 10;                     // pairs per thread
constexpr int TPB = SZ * SY * SX;           // 10240 half2 = 40 KB

typedef float f4 __attribute__((ext_vector_type(4)));

struct h2p { __half2 a, b; };               // (ch0,ch1)@x , (ch0,ch1)@x+1
__device__ __forceinline__ h2p    ld_pair(const __half2* p){ h2p v; __builtin_memcpy(&v,p,8); return v; }
__device__ __forceinline__ void   st_pair(__half2* p, h2p v){ __builtin_memcpy(p,&v,8); }
__device__ __forceinline__ float2 ld2f(const float* p){ float2 v; __builtin_memcpy(&v,p,8); return v; }
__device__ __forceinline__ f4     ld4f(const float* p){ f4 v; __builtin_memcpy(&v,p,16); return v; }
__device__ __forceinline__ void   st4f(float* p, f4 v){ __builtin_memcpy(p,&v,16); }

__global__ __launch_bounds__(NTHR, 8) void warp3d_r18_kernel(
    const float* __restrict__ src,
    const float* __restrict__ flow,
    float* __restrict__ out)
{
    __shared__ __half2 tile[TPB];           // 40 KB

    const float* src0 = src;
    const float* src1 = src + N;
    const float* f0 = flow, * f1 = flow + N, * f2 = flow + 2 * N;
    float* out0 = out, * out1 = out + N;

    const int tid = threadIdx.x;
    const int bx = blockIdx.x, by = blockIdx.y, bz = blockIdx.z;
    const int tz0 = bz * BZ - HA, ty0 = by * BY - HA, tx0 = bx * BX - HA;
    const int tbase = (bz * BZ * H + by * BY) * W + bx * BX;

    // ---- flow quad for this thread (4 consecutive x), 16B-aligned f4 loads ----
    const int qm = tid & 7, qd = tid >> 3;  // qd in [0,64)
    const int lx = qm << 2, ly = qd & 7, lz = qd >> 3;
    const int vi = tbase + (lz * H + ly) * W + lx;
    const f4 fz4 = ld4f(f0 + vi);
    const f4 fy4 = ld4f(f1 + vi);
    const f4 fx4 = ld4f(f2 + vi);

    // ---- stage, phase 1: issue ALL 20 loads (one vmcnt ramp, no waits) ----
    float2 sA[NPP], sB[NPP];
    int rowk[NPP], colk[NPP];
    bool s0k[NPP], s1k[NPP];
    #pragma unroll
    for (int k = 0; k < NPP; ++k) {
        const int pi  = tid + k * NTHR;
        const int row = pi / SXP;           // const-div -> magic mul
        const int col = pi - row * SXP;
        const int s = row >> 4, t = row & 15;
        const int gz = min(max(tz0 + s, 0), D - 1);
        const int gy = min(max(ty0 + t, 0), H - 1);
        const int b  = tx0 + (col << 1);
        const int bc = min(max(b, 0), W - 2);
        const int ga = (gz * H + gy) * W + bc;
        rowk[k] = row; colk[k] = col;
        s0k[k] = (min(max(b,     0), W - 1) > bc);
        s1k[k] = (min(max(b + 1, 0), W - 1) > bc);
        sA[k] = ld2f(src0 + ga);
        sB[k] = ld2f(src1 + ga);
    }
    // ---- stage, phase 2: cvt + ds_write (compiler inserts the single wait) ----
    #pragma unroll
    for (int k = 0; k < NPP; ++k) {
        h2p v;
        v.a = __floats2half2_rn(s0k[k] ? sA[k].y : sA[k].x, s0k[k] ? sB[k].y : sB[k].x);
        v.b = __floats2half2_rn(s1k[k] ? sA[k].y : sA[k].x, s1k[k] ? sB[k].y : sB[k].x);
        st_pair(&tile[rowk[k] * SX + (colk[k] << 1)], v);
    }
    __syncthreads();

    // ---- gather: one x-quad per thread, packed-half2 lerp, float4 out ----
    const float pz_b = (float)(bz * BZ + lz);
    const float py_b = (float)(by * BY + ly);
    const float px_b = (float)(bx * BX + lx);

    float a0s[4], a1s[4];

    #pragma unroll
    for (int i = 0; i < 4; ++i) {
        const float pz = fz4[i] + pz_b;
        const float py = fy4[i] + py_b;
        const float px = fx4[i] + (px_b + (float)i);

        const float z0f = floorf(pz), y0f = floorf(py), x0f = floorf(px);
        const float fz = pz - z0f, fy = py - y0f, fx = px - x0f;
        const int z0 = (int)z0f, y0 = (int)y0f, x0 = (int)x0f;

        // zeros padding folded into per-axis weights (validity on GLOBAL coords)
        const float wz0 = ((unsigned)z0       < (unsigned)D) ? (1.0f - fz) : 0.0f;
        const float wz1 = ((unsigned)(z0 + 1) < (unsigned)D) ? fz          : 0.0f;
        const float wy0 = ((unsigned)y0       < (unsigned)H) ? (1.0f - fy) : 0.0f;
        const float wy1 = ((unsigned)(y0 + 1) < (unsigned)H) ? fy          : 0.0f;
        const float wx0 = ((unsigned)x0       < (unsigned)W) ? (1.0f - fx) : 0.0f;
        const float wx1 = ((unsigned)(x0 + 1) < (unsigned)W) ? fx          : 0.0f;

        const int a0 = z0 - tz0;
        const int b0 = y0 - ty0;
        const int u0 = x0 - tx0;
        const bool intile = ((unsigned)a0 < (unsigned)(SZ - 1)) &&
                            ((unsigned)b0 < (unsigned)(SY - 1)) &&
                            ((unsigned)u0 < (unsigned)(SX - 1));

        if (intile) {
            const __half2 wxh0 = __float2half2_rn(wx0);
            const __half2 wxh1 = __float2half2_rn(wx1);
            const __half2 w00h = __float2half2_rn(wz0 * wy0);
            const __half2 w01h = __float2half2_rn(wz0 * wy1);
            const __half2 w10h = __float2half2_rn(wz1 * wy0);
            const __half2 w11h = __float2half2_rn(wz1 * wy1);

            const int r00 = (a0 * SY + b0) * SX + u0;
            const h2p q00 = ld_pair(&tile[r00]);
            const h2p q01 = ld_pair(&tile[r00 + SX]);
            const h2p q10 = ld_pair(&tile[r00 + SY * SX]);
            const h2p q11 = ld_pair(&tile[r00 + SY * SX + SX]);

            // packed x-lerp (both channels per op), then packed y/z accumulation
            const __half2 xl00 = __hfma2(q00.b, wxh1, __hmul2(q00.a, wxh0));
            const __half2 xl01 = __hfma2(q01.b, wxh1, __hmul2(q01.a, wxh0));
            const __half2 xl10 = __hfma2(q10.b, wxh1, __hmul2(q10.a, wxh0));
            const __half2 xl11 = __hfma2(q11.b, wxh1, __hmul2(q11.a, wxh0));

            const __half2 acc = __hfma2(xl11, w11h,
                                __hfma2(xl10, w10h,
                                __hfma2(xl01, w01h,
                                __hmul2(xl00, w00h))));
            const float2 g = __half22float2(acc);
            a0s[i] = g.x;
            a1s[i] = g.y;
        } else {
            // |flow| >= 4 near a tile face (P ~ 1e-5): exact fp32 global fallback
            const float w00 = wz0 * wy0, w01 = wz0 * wy1;
            const float w10 = wz1 * wy0, w11 = wz1 * wy1;
            const int zc0 = min(max(z0, 0), D - 1), zc1 = min(max(z0 + 1, 0), D - 1);
            const int yc0 = min(max(y0, 0), H - 1), yc1 = min(max(y0 + 1, 0), H - 1);
            const int xc0 = min(max(x0, 0), W - 1), xc1 = min(max(x0 + 1, 0), W - 1);
            const int g00 = (zc0 * H + yc0) * W, g01 = (zc0 * H + yc1) * W;
            const int g10 = (zc1 * H + yc0) * W, g11 = (zc1 * H + yc1) * W;
            a0s[i] = w00 * (wx0 * src0[g00 + xc0] + wx1 * src0[g00 + xc1])
                   + w01 * (wx0 * src0[g01 + xc0] + wx1 * src0[g01 + xc1])
                   + w10 * (wx0 * src0[g10 + xc0] + wx1 * src0[g10 + xc1])
                   + w11 * (wx0 * src0[g11 + xc0] + wx1 * src0[g11 + xc1]);
            a1s[i] = w00 * (wx0 * src1[g00 + xc0] + wx1 * src1[g00 + xc1])
                   + w01 * (wx0 * src1[g01 + xc0] + wx1 * src1[g01 + xc1])
                   + w10 * (wx0 * src1[g10 + xc0] + wx1 * src1[g10 + xc1])
                   + w11 * (wx0 * src1[g11 + xc0] + wx1 * src1[g11 + xc1]);
        }
    }

    f4 o0 = { a0s[0], a0s[1], a0s[2], a0s[3] };
    f4 o1 = { a1s[0], a1s[1], a1s[2], a1s[3] };
    st4f(out0 + vi, o0);
    st4f(out1 + vi, o1);
}

extern "C" void kernel_launch(void* const* d_in, const int* in_sizes, int n_in,
                              void* d_out, int out_size, void* d_ws, size_t ws_size,
                              hipStream_t stream) {
    const float* src  = (const float*)d_in[0];
    const float* flow = (const float*)d_in[1];
    float* out = (float*)d_out;

    dim3 grid(W / BX, H / BY, D / BZ);      // 7 x 24 x 20 = 3360 blocks
    warp3d_r18_kernel<<<grid, NTHR, 0, stream>>>(src, flow, out);
}